// Round 1
// baseline (390.784 us; speedup 1.0000x reference)
//
#include <hip/hip_runtime.h>
#include <math.h>

// Problem constants
#define S 192
#define H 64
#define NH 8           // b*n = 1*8
#define SC 0.125f
#define FILLV (-1000000.0f)

// ---------------- wave (64-lane) reductions ----------------
__device__ __forceinline__ float wave_max(float v) {
#pragma unroll
  for (int m = 32; m; m >>= 1) v = fmaxf(v, __shfl_xor(v, m));
  return v;
}
__device__ __forceinline__ float wave_sum(float v) {
#pragma unroll
  for (int m = 32; m; m >>= 1) v += __shfl_xor(v, m);
  return v;
}

// ---------------- Kernel A: kk = k1*k2^T, qk = k2*q^T, sv1 = silu(v1) ----------------
// blocks 0..287   : kk tiles  (8 heads x 6x6 tiles of 32x32, K=64)
// blocks 288..575 : qk tiles
// blocks 576..671 : silu(v1) (float4 elementwise)
__global__ void prep_kernel(const float* __restrict__ q, const float* __restrict__ k1,
                            const float* __restrict__ k2, const float* __restrict__ v1,
                            float* __restrict__ kk, float* __restrict__ qk,
                            float* __restrict__ sv1) {
  int b = blockIdx.x;
  if (b < 576) {
    bool is_kk = (b < 288);
    int bb = is_kk ? b : b - 288;
    int n = bb / 36;
    int rem = bb % 36;
    int rt = (rem / 6) * 32;   // row tile base (s for kk, t for qk)
    int ct = (rem % 6) * 32;   // col tile base (t for kk, q for qk)
    const float* Abase = (is_kk ? k1 : k2) + n * S * H;
    const float* Bbase = (is_kk ? k2 : q) + n * S * H;
    float* out = (is_kk ? kk : qk) + n * S * S;

    __shared__ float As[32][65];
    __shared__ float Bs[32][65];
    int tid = threadIdx.x;
    for (int i = tid; i < 32 * 64; i += 256) {
      int r = i >> 6, h = i & 63;
      As[r][h] = Abase[(rt + r) * H + h];
      Bs[r][h] = Bbase[(ct + r) * H + h];
    }
    __syncthreads();
    int r0 = (tid / 16) * 2, c0 = (tid % 16) * 2;
    float a00 = 0.f, a01 = 0.f, a10 = 0.f, a11 = 0.f;
#pragma unroll
    for (int h = 0; h < 64; ++h) {
      float x0 = As[r0][h], x1 = As[r0 + 1][h];
      float y0 = Bs[c0][h], y1 = Bs[c0 + 1][h];
      a00 += x0 * y0; a01 += x0 * y1; a10 += x1 * y0; a11 += x1 * y1;
    }
    out[(rt + r0) * S + ct + c0]         = a00;
    out[(rt + r0) * S + ct + c0 + 1]     = a01;
    out[(rt + r0 + 1) * S + ct + c0]     = a10;
    out[(rt + r0 + 1) * S + ct + c0 + 1] = a11;
  } else {
    int i = (b - 576) * 256 + threadIdx.x;   // 96 blocks * 256 = 24576 float4 = 98304 floats
    const float4* v4 = (const float4*)v1;
    float4 x = v4[i];
    float4 y;
    y.x = x.x / (1.f + expf(-x.x));
    y.y = x.y / (1.f + expf(-x.y));
    y.z = x.z / (1.f + expf(-x.z));
    y.w = x.w / (1.f + expf(-x.w));
    ((float4*)sv1)[i] = y;
  }
}

// ---------------- Kernel D: per-t stats m_t, S_t and A[t,h] ----------------
// grid = NH*S blocks, 64 threads (lane = h)
__global__ void stats_kernel(const float* __restrict__ kk, const float* __restrict__ sv1,
                             float* __restrict__ mt, float* __restrict__ St,
                             float* __restrict__ Aw) {
  int n = blockIdx.x / S, t = blockIdx.x % S;
  int lane = threadIdx.x;
  __shared__ float w[S];
  const float* kkc = kk + n * S * S + t;   // element [s] at kkc[s*S]

  float lm = -3.4e38f;
  for (int s = lane; s <= t; s += 64) lm = fmaxf(lm, SC * kkc[s * S]);
  float m = wave_max(lm);

  float ls = 0.f;
  for (int s = lane; s <= t; s += 64) {
    float e = expf(SC * kkc[s * S] - m);
    w[s] = e;
    ls += e;
  }
  float Ssum = wave_sum(ls);
  if (lane == 0) { mt[n * S + t] = m; St[n * S + t] = Ssum; }
  __syncthreads();

  const float* sh = sv1 + n * S * H + lane;
  float acc = 0.f;
  for (int s = 0; s <= t; ++s) acc += w[s] * sh[s * H];
  Aw[(n * S + t) * H + lane] = acc;
}

// ---------------- Kernel E: per-q M0, D, z, M ----------------
// grid = NH*S blocks, 64 threads (lane = h)
__global__ void out_kernel(const float* __restrict__ qk, const float* __restrict__ v2,
                           const float* __restrict__ mt, const float* __restrict__ St,
                           const float* __restrict__ Aw,
                           float* __restrict__ z, float* __restrict__ Mout) {
  int n = blockIdx.x / S, qq = blockIdx.x % S;
  int lane = threadIdx.x;
  __shared__ float e[S];
  const float* qkc = qk + n * S * S + qq;  // element [t] at qkc[t*S]

  float lm = -3.4e38f;
  for (int t = lane; t <= qq; t += 64) lm = fmaxf(lm, SC * qkc[t * S] + mt[n * S + t]);
  float M0 = wave_max(lm);

  float ls = 0.f;
  for (int t = lane; t <= qq; t += 64) {
    float ev = expf(SC * qkc[t * S] + mt[n * S + t] - M0);
    e[t] = ev;
    ls += ev * St[n * S + t];
  }
  float D = wave_sum(ls);
  if (lane == 0) Mout[n * S + qq] = M0 + logf(D + 0.01f);
  __syncthreads();

  const float* vh = v2 + n * S * H + lane;
  const float* Ah = Aw + n * S * H + lane;
  float acc = 0.f;
  for (int t = 0; t <= qq; ++t) acc += e[t] * vh[t * H] * Ah[t * H];
  z[(n * S + qq) * H + lane] = acc / D;
}

// ---------------- Kernel B: pre_softmax_attn_score [n,s,t,q] (226 MB stream) ----------------
// grid = NH*S blocks (one per (n,s)), 256 threads, float4 stores
__global__ void score_kernel(const float* __restrict__ kk, const float* __restrict__ qk,
                             float* __restrict__ score) {
  int n = blockIdx.x / S, s = blockIdx.x % S;
  const float* kkr = kk + (n * S + s) * S;           // kk[s][t]
  const float4* qk4 = (const float4*)(qk + n * S * S);
  float4* out4 = (float4*)(score + (size_t)(n * S + s) * S * S);
  const float4 fill = make_float4(FILLV, FILLV, FILLV, FILLV);

  for (int i = threadIdx.x; i < S * 48; i += 256) {   // 48 float4 per q-row
    int t = i / 48, j = i - t * 48;
    float4 v;
    if (t < s) {
      v = fill;                                       // s > t fully masked
    } else {
      float kv = kkr[t];
      float4 qv = qk4[t * 48 + j];
      int q0 = 4 * j;
      v.x = (t > q0)     ? FILLV : kv + qv.x;         // t > q masked
      v.y = (t > q0 + 1) ? FILLV : kv + qv.y;
      v.z = (t > q0 + 2) ? FILLV : kv + qv.z;
      v.w = (t > q0 + 3) ? FILLV : kv + qv.w;
    }
    out4[i] = v;
  }
}

// ---------------- Kernel C: v_gated [n,s,t,h] = silu(v1[s,h]) * v2[t,h] (75 MB stream) ----------------
// grid = NH*S blocks (one per (n,s)), 256 threads, float4 stores
__global__ void vg_kernel(const float* __restrict__ sv1, const float* __restrict__ v2,
                          float* __restrict__ vg) {
  int n = blockIdx.x / S, s = blockIdx.x % S;
  const float4* a4 = (const float4*)(sv1 + (n * S + s) * H);
  const float4* b4 = (const float4*)(v2 + n * S * H);
  float4* out4 = (float4*)(vg + (size_t)(n * S + s) * S * H);

  for (int i = threadIdx.x; i < S * 16; i += 256) {   // 16 float4 per h-row
    int t = i >> 4, j = i & 15;
    float4 a = a4[j];
    float4 b = b4[t * 16 + j];
    out4[i] = make_float4(a.x * b.x, a.y * b.y, a.z * b.z, a.w * b.w);
  }
}

extern "C" void kernel_launch(void* const* d_in, const int* in_sizes, int n_in,
                              void* d_out, int out_size, void* d_ws, size_t ws_size,
                              hipStream_t stream) {
  const float* q  = (const float*)d_in[0];
  const float* k1 = (const float*)d_in[1];
  const float* k2 = (const float*)d_in[2];
  const float* v1 = (const float*)d_in[3];
  const float* v2 = (const float*)d_in[4];
  float* out = (float*)d_out;

  // Output layout (concatenated flat, return order): z, pre_score, v_gated, M
  float* z     = out;                            // 8*192*64       = 98304
  float* score = out + 98304;                    // 8*192*192*192  = 56623104
  float* vg    = out + 98304 + 56623104;         // 8*192*192*64   = 18874368
  float* Mout  = out + 98304 + 56623104 + 18874368; // 8*192      = 1536

  // Workspace layout (floats)
  float* ws  = (float*)d_ws;
  float* kk  = ws;                 // 8*192*192 = 294912
  float* qk  = ws + 294912;        // 294912
  float* sv1 = ws + 589824;        // 8*192*64  = 98304
  float* mt  = ws + 688128;        // 1536
  float* St  = ws + 689664;        // 1536
  float* Aw  = ws + 691200;        // 98304   -> total 789504 floats (~3.2 MB)

  prep_kernel<<<dim3(672), dim3(256), 0, stream>>>(q, k1, k2, v1, kk, qk, sv1);
  stats_kernel<<<dim3(NH * S), dim3(64), 0, stream>>>(kk, sv1, mt, St, Aw);
  out_kernel<<<dim3(NH * S), dim3(64), 0, stream>>>(qk, v2, mt, St, Aw, z, Mout);
  score_kernel<<<dim3(NH * S), dim3(256), 0, stream>>>(kk, qk, score);
  vg_kernel<<<dim3(NH * S), dim3(256), 0, stream>>>(sv1, v2, vg);
}

// Round 3
// 356.858 us; speedup vs baseline: 1.0951x; 1.0951x over previous
//
#include <hip/hip_runtime.h>
#include <math.h>

// Problem constants
#define S 192
#define H 64
#define NH 8           // b*n = 1*8
#define SC 0.125f
#define FILLV (-1000000.0f)

// native 4-float vector usable with __builtin_nontemporal_store
typedef float floatx4 __attribute__((ext_vector_type(4)));

// ---------------- wave (64-lane) reductions ----------------
__device__ __forceinline__ float wave_max(float v) {
#pragma unroll
  for (int m = 32; m; m >>= 1) v = fmaxf(v, __shfl_xor(v, m));
  return v;
}
__device__ __forceinline__ float wave_sum(float v) {
#pragma unroll
  for (int m = 32; m; m >>= 1) v += __shfl_xor(v, m);
  return v;
}

// ---------------- Kernel A: kk = k1*k2^T, qk = k2*q^T, sv1 = silu(v1) ----------------
// blocks 0..287   : kk tiles  (8 heads x 6x6 tiles of 32x32, K=64)
// blocks 288..575 : qk tiles
// blocks 576..671 : silu(v1) (float4 elementwise)
__global__ void prep_kernel(const float* __restrict__ q, const float* __restrict__ k1,
                            const float* __restrict__ k2, const float* __restrict__ v1,
                            float* __restrict__ kk, float* __restrict__ qk,
                            float* __restrict__ sv1) {
  int b = blockIdx.x;
  if (b < 576) {
    bool is_kk = (b < 288);
    int bb = is_kk ? b : b - 288;
    int n = bb / 36;
    int rem = bb % 36;
    int rt = (rem / 6) * 32;   // row tile base (s for kk, t for qk)
    int ct = (rem % 6) * 32;   // col tile base (t for kk, q for qk)
    const float* Abase = (is_kk ? k1 : k2) + n * S * H;
    const float* Bbase = (is_kk ? k2 : q) + n * S * H;
    float* out = (is_kk ? kk : qk) + n * S * S;

    __shared__ float As[32][65];
    __shared__ float Bs[32][65];
    int tid = threadIdx.x;
    for (int i = tid; i < 32 * 64; i += 256) {
      int r = i >> 6, h = i & 63;
      As[r][h] = Abase[(rt + r) * H + h];
      Bs[r][h] = Bbase[(ct + r) * H + h];
    }
    __syncthreads();
    int r0 = (tid / 16) * 2, c0 = (tid % 16) * 2;
    float a00 = 0.f, a01 = 0.f, a10 = 0.f, a11 = 0.f;
#pragma unroll
    for (int h = 0; h < 64; ++h) {
      float x0 = As[r0][h], x1 = As[r0 + 1][h];
      float y0 = Bs[c0][h], y1 = Bs[c0 + 1][h];
      a00 += x0 * y0; a01 += x0 * y1; a10 += x1 * y0; a11 += x1 * y1;
    }
    out[(rt + r0) * S + ct + c0]         = a00;
    out[(rt + r0) * S + ct + c0 + 1]     = a01;
    out[(rt + r0 + 1) * S + ct + c0]     = a10;
    out[(rt + r0 + 1) * S + ct + c0 + 1] = a11;
  } else {
    int i = (b - 576) * 256 + threadIdx.x;   // 96 blocks * 256 = 24576 float4
    const float4* v4 = (const float4*)v1;
    float4 x = v4[i];
    float4 y;
    y.x = x.x / (1.f + expf(-x.x));
    y.y = x.y / (1.f + expf(-x.y));
    y.z = x.z / (1.f + expf(-x.z));
    y.w = x.w / (1.f + expf(-x.w));
    ((float4*)sv1)[i] = y;
  }
}

// ---------------- Kernel D: per-t stats m_t, S_t and A[t,h] ----------------
// grid = NH*S blocks, 256 threads (4 waves split the s-axis)
__global__ __launch_bounds__(256) void stats_kernel(
    const float* __restrict__ kk, const float* __restrict__ sv1,
    float* __restrict__ mt, float* __restrict__ St, float* __restrict__ Aw) {
  int n = blockIdx.x / S, t = blockIdx.x % S;
  int tid = threadIdx.x, wv = tid >> 6, lane = tid & 63;
  __shared__ float w[S];
  __shared__ float red[4];
  __shared__ float part[4][H];
  const float* kkc = kk + n * S * S + t;   // element [s] at kkc[s*S]

  float lm = -3.4e38f;
  for (int s = tid; s <= t; s += 256) lm = fmaxf(lm, SC * kkc[s * S]);
  lm = wave_max(lm);
  if (lane == 0) red[wv] = lm;
  __syncthreads();
  float m = fmaxf(fmaxf(red[0], red[1]), fmaxf(red[2], red[3]));

  float ls = 0.f;
  for (int s = tid; s <= t; s += 256) {
    float e = expf(SC * kkc[s * S] - m);
    w[s] = e;
    ls += e;
  }
  ls = wave_sum(ls);
  __syncthreads();
  if (lane == 0) red[wv] = ls;
  __syncthreads();
  float Ssum = red[0] + red[1] + red[2] + red[3];
  if (tid == 0) { mt[n * S + t] = m; St[n * S + t] = Ssum; }

  // A[t,h] = sum_{s<=t} w[s]*sv1[s,h]; 4 waves split s, lane = h
  const float* sh = sv1 + n * S * H + lane;
  float acc = 0.f;
  for (int s = wv; s <= t; s += 4) acc += w[s] * sh[s * H];
  part[wv][lane] = acc;
  __syncthreads();
  if (wv == 0)
    Aw[(n * S + t) * H + lane] = part[0][lane] + part[1][lane] + part[2][lane] + part[3][lane];
}

// ---------------- Kernel E: per-q M0, D, z, M ----------------
// grid = NH*S blocks, 256 threads (4 waves split the t-axis)
__global__ __launch_bounds__(256) void out_kernel(
    const float* __restrict__ qk, const float* __restrict__ v2,
    const float* __restrict__ mt, const float* __restrict__ St,
    const float* __restrict__ Aw,
    float* __restrict__ z, float* __restrict__ Mout) {
  int n = blockIdx.x / S, qq = blockIdx.x % S;
  int tid = threadIdx.x, wv = tid >> 6, lane = tid & 63;
  __shared__ float e[S];
  __shared__ float red[4];
  __shared__ float part[4][H];
  const float* qkc = qk + n * S * S + qq;  // element [t] at qkc[t*S]
  const float* mtp = mt + n * S;
  const float* Stp = St + n * S;

  float lm = -3.4e38f;
  for (int t = tid; t <= qq; t += 256) lm = fmaxf(lm, SC * qkc[t * S] + mtp[t]);
  lm = wave_max(lm);
  if (lane == 0) red[wv] = lm;
  __syncthreads();
  float M0 = fmaxf(fmaxf(red[0], red[1]), fmaxf(red[2], red[3]));

  float ls = 0.f;
  for (int t = tid; t <= qq; t += 256) {
    float ev = expf(SC * qkc[t * S] + mtp[t] - M0);
    e[t] = ev;
    ls += ev * Stp[t];
  }
  ls = wave_sum(ls);
  __syncthreads();
  if (lane == 0) red[wv] = ls;
  __syncthreads();
  float D = red[0] + red[1] + red[2] + red[3];
  if (tid == 0) Mout[n * S + qq] = M0 + logf(D + 0.01f);

  const float* vh = v2 + n * S * H + lane;
  const float* Ah = Aw + n * S * H + lane;
  float acc = 0.f;
  for (int t = wv; t <= qq; t += 4) acc += e[t] * vh[t * H] * Ah[t * H];
  part[wv][lane] = acc;
  __syncthreads();
  if (wv == 0)
    z[(n * S + qq) * H + lane] =
        (part[0][lane] + part[1][lane] + part[2][lane] + part[3][lane]) / D;
}

// ---------------- Kernel B: pre_softmax_attn_score [n,s,t,q] (226 MB stream) ----------------
// grid = NH*S blocks (one per (n,s)), 512 threads, nontemporal float4 stores
__global__ __launch_bounds__(512) void score_kernel(
    const float* __restrict__ kk, const float* __restrict__ qk,
    float* __restrict__ score) {
  int n = blockIdx.x / S, s = blockIdx.x % S;
  const float* kkr = kk + (n * S + s) * S;           // kk[s][t]
  const float4* qk4 = (const float4*)(qk + n * S * S);
  floatx4* out4 = (floatx4*)(score + (size_t)(n * S + s) * S * S);

  for (int i = threadIdx.x; i < S * 48; i += 512) {   // 48 float4 per q-row
    int t = i / 48, j = i - t * 48;
    floatx4 v;
    if (t < s) {
      v = (floatx4){FILLV, FILLV, FILLV, FILLV};      // s > t fully masked
    } else {
      float kv = kkr[t];
      float4 qv = qk4[t * 48 + j];
      int q0 = 4 * j;
      v.x = (t > q0)     ? FILLV : kv + qv.x;         // t > q masked
      v.y = (t > q0 + 1) ? FILLV : kv + qv.y;
      v.z = (t > q0 + 2) ? FILLV : kv + qv.z;
      v.w = (t > q0 + 3) ? FILLV : kv + qv.w;
    }
    __builtin_nontemporal_store(v, &out4[i]);
  }
}

// ---------------- Kernel C: v_gated [n,s,t,h] = silu(v1[s,h]) * v2[t,h] (75 MB stream) ----------------
// grid = NH*S blocks (one per (n,s)), 256 threads, nontemporal float4 stores
__global__ __launch_bounds__(256) void vg_kernel(
    const float* __restrict__ sv1, const float* __restrict__ v2,
    float* __restrict__ vg) {
  int n = blockIdx.x / S, s = blockIdx.x % S;
  const float4* a4 = (const float4*)(sv1 + (n * S + s) * H);
  const float4* b4 = (const float4*)(v2 + n * S * H);
  floatx4* out4 = (floatx4*)(vg + (size_t)(n * S + s) * S * H);

  for (int i = threadIdx.x; i < S * 16; i += 256) {   // 16 float4 per h-row
    int t = i >> 4, j = i & 15;
    float4 a = a4[j];
    float4 b = b4[t * 16 + j];
    floatx4 v = (floatx4){a.x * b.x, a.y * b.y, a.z * b.z, a.w * b.w};
    __builtin_nontemporal_store(v, &out4[i]);
  }
}

extern "C" void kernel_launch(void* const* d_in, const int* in_sizes, int n_in,
                              void* d_out, int out_size, void* d_ws, size_t ws_size,
                              hipStream_t stream) {
  const float* q  = (const float*)d_in[0];
  const float* k1 = (const float*)d_in[1];
  const float* k2 = (const float*)d_in[2];
  const float* v1 = (const float*)d_in[3];
  const float* v2 = (const float*)d_in[4];
  float* out = (float*)d_out;

  // Output layout (concatenated flat, return order): z, pre_score, v_gated, M
  float* z     = out;                                  // 8*192*64       = 98304
  float* score = out + 98304;                          // 8*192*192*192  = 56623104
  float* vg    = out + 98304 + 56623104;               // 8*192*192*64   = 18874368
  float* Mout  = out + 98304 + 56623104 + 18874368;    // 8*192          = 1536

  // Workspace layout (floats)
  float* ws  = (float*)d_ws;
  float* kk  = ws;                 // 8*192*192 = 294912
  float* qk  = ws + 294912;        // 294912
  float* sv1 = ws + 589824;        // 8*192*64  = 98304
  float* mt  = ws + 688128;        // 1536
  float* St  = ws + 689664;        // 1536
  float* Aw  = ws + 691200;        // 98304   -> total ~3.2 MB

  prep_kernel<<<dim3(672), dim3(256), 0, stream>>>(q, k1, k2, v1, kk, qk, sv1);
  stats_kernel<<<dim3(NH * S), dim3(256), 0, stream>>>(kk, sv1, mt, St, Aw);
  out_kernel<<<dim3(NH * S), dim3(256), 0, stream>>>(qk, v2, mt, St, Aw, z, Mout);
  score_kernel<<<dim3(NH * S), dim3(512), 0, stream>>>(kk, qk, score);
  vg_kernel<<<dim3(NH * S), dim3(256), 0, stream>>>(sv1, v2, vg);
}